// Round 1
// baseline (1455.628 us; speedup 1.0000x reference)
//
#include <hip/hip_runtime.h>

#define NEG_SLOPE 0.2f

// ---------------- GEMM: C[M,N] = A[M,K] @ B[K,N], fp32, tiled ----------------
template<int BM, int BN, int BK>
__global__ __launch_bounds__(256)
void gemm_kernel(const float* __restrict__ A, const float* __restrict__ B,
                 float* __restrict__ C, int M, int N, int K) {
  __shared__ float As[BK][BM + 4];
  __shared__ float Bs[BK][BN + 4];
  const int bm = blockIdx.x * BM;
  const int bn = blockIdx.y * BN;
  const int tid = threadIdx.x;
  const int tr = (tid / (BN / 4)) * 4;   // 0..BM-4
  const int tc = (tid % (BN / 4)) * 4;   // 0..BN-4
  float acc[4][4] = {};
  for (int k0 = 0; k0 < K; k0 += BK) {
    for (int i = tid; i < BM * BK; i += 256) {
      int r = i / BK, c = i % BK;
      int gr = bm + r;
      As[c][r] = (gr < M) ? A[(size_t)gr * K + k0 + c] : 0.f;
    }
    for (int i = tid; i < BK * BN; i += 256) {
      int r = i / BN, c = i % BN;
      Bs[r][c] = B[(size_t)(k0 + r) * N + bn + c];
    }
    __syncthreads();
#pragma unroll
    for (int k = 0; k < BK; ++k) {
      float a[4], b[4];
#pragma unroll
      for (int i = 0; i < 4; i++) a[i] = As[k][tr + i];
#pragma unroll
      for (int j = 0; j < 4; j++) b[j] = Bs[k][tc + j];
#pragma unroll
      for (int i = 0; i < 4; i++)
#pragma unroll
        for (int j = 0; j < 4; j++) acc[i][j] += a[i] * b[j];
    }
    __syncthreads();
  }
#pragma unroll
  for (int i = 0; i < 4; i++) {
    int r = bm + tr + i;
    if (r < M) {
#pragma unroll
      for (int j = 0; j < 4; j++) C[(size_t)r * N + bn + tc + j] = acc[i][j];
    }
  }
}

// ---------------- per-(node,head) attention halves ----------------
__global__ void node_att_kernel(const float* __restrict__ h,
                                const float* __restrict__ a_src,
                                const float* __restrict__ a_dst,
                                float* __restrict__ al_s, float* __restrict__ al_d,
                                int N) {
  int i = blockIdx.x * blockDim.x + threadIdx.x;  // over N*4
  if (i >= N * 4) return;
  int n = i >> 2, hd = i & 3;
  const float* hp = h + (size_t)n * 128 + hd * 32;
  const float* as = a_src + hd * 32;
  const float* ad = a_dst + hd * 32;
  float ss = 0.f, sd = 0.f;
#pragma unroll
  for (int d = 0; d < 32; ++d) {
    float v = hp[d];
    ss += v * as[d];
    sd += v * ad[d];
  }
  al_s[i] = ss;
  al_d[i] = sd;
}

// ---------------- edge pass A: softmax denominator ----------------
__global__ void edge_a_kernel(const int* __restrict__ src, const int* __restrict__ dst,
                              const float* __restrict__ al_s, const float* __restrict__ al_d,
                              float* __restrict__ denom, int E) {
  int i = blockIdx.x * blockDim.x + threadIdx.x;  // over E*4
  if (i >= E * 4) return;
  int e = i >> 2, hd = i & 3;
  int s = src[e], d = dst[e];
  float a = al_s[s * 4 + hd] + al_d[d * 4 + hd];
  a = a > 0.f ? a : NEG_SLOPE * a;
  atomicAdd(&denom[d * 4 + hd], expf(a));
}

// ---------------- edge pass B: weighted scatter of h[src] ----------------
__global__ void edge_b_kernel(const int* __restrict__ src, const int* __restrict__ dst,
                              const float* __restrict__ h,
                              const float* __restrict__ al_s, const float* __restrict__ al_d,
                              const float* __restrict__ denom,
                              float* __restrict__ out, int E) {
  int i = blockIdx.x * blockDim.x + threadIdx.x;  // over E*128 = 102.4M (fits int)
  if (i >= E * 128) return;
  int e = i >> 7;
  int f = i & 127;
  int hd = f >> 5;
  int s = src[e], d = dst[e];
  float a = al_s[s * 4 + hd] + al_d[d * 4 + hd];
  a = a > 0.f ? a : NEG_SLOPE * a;
  float w = expf(a) / (denom[d * 4 + hd] + 1e-16f);
  atomicAdd(&out[(size_t)d * 128 + f], h[(size_t)s * 128 + f] * w);
}

// ---------------- add summed bias ----------------
__global__ void bias_kernel(float* __restrict__ out, const float* __restrict__ bias,
                            int N) {
  int i = blockIdx.x * blockDim.x + threadIdx.x;  // over N*128
  if (i >= N * 128) return;
  int f = i & 127;
  out[i] += bias[f] + bias[128 + f] + bias[256 + f];
}

extern "C" void kernel_launch(void* const* d_in, const int* in_sizes, int n_in,
                              void* d_out, int out_size, void* d_ws, size_t ws_size,
                              hipStream_t stream) {
  const float* x     = (const float*)d_in[0];
  const int*   ei[3] = {(const int*)d_in[1], (const int*)d_in[2], (const int*)d_in[3]};
  const float* W     = (const float*)d_in[4];
  const float* a_src = (const float*)d_in[5];
  const float* a_dst = (const float*)d_in[6];
  const float* bias  = (const float*)d_in[7];

  const int Fin = 256, Fout = 128, H = 4, D = 32, R = 3;
  const int N = in_sizes[0] / Fin;

  float* out = (float*)d_out;

  // workspace layout (floats): h[N*128] | al_s[N*4] | al_d[N*4] | denom[N*4]
  float* h     = (float*)d_ws;
  float* al_s  = h + (size_t)N * Fout;
  float* al_d  = al_s + (size_t)N * H;
  float* denom = al_d + (size_t)N * H;

  hipMemsetAsync(d_out, 0, (size_t)out_size * sizeof(float), stream);

  for (int r = 0; r < R; ++r) {
    const int E = in_sizes[1 + r] / 2;
    const int* srcp = ei[r];
    const int* dstp = ei[r] + E;

    hipMemsetAsync(denom, 0, (size_t)N * H * sizeof(float), stream);

    dim3 gg((N + 63) / 64, Fout / 64);
    gemm_kernel<64, 64, 16><<<gg, 256, 0, stream>>>(
        x, W + (size_t)r * Fin * Fout, h, N, Fout, Fin);

    int na = N * H;
    node_att_kernel<<<(na + 255) / 256, 256, 0, stream>>>(
        h, a_src + r * H * D, a_dst + r * H * D, al_s, al_d, N);

    int ea = E * H;
    edge_a_kernel<<<(ea + 255) / 256, 256, 0, stream>>>(
        srcp, dstp, al_s, al_d, denom, E);

    long eb = (long)E * Fout;
    edge_b_kernel<<<(int)((eb + 255) / 256), 256, 0, stream>>>(
        srcp, dstp, h, al_s, al_d, denom, out, E);
  }

  bias_kernel<<<(N * Fout + 255) / 256, 256, 0, stream>>>(out, bias, N);
}

// Round 2
// 873.309 us; speedup vs baseline: 1.6668x; 1.6668x over previous
//
#include <hip/hip_runtime.h>

#define NEG_SLOPE 0.2f
#define MAXE_LDS 256   // per-dst edge cache in LDS (deg>256 falls back to recompute)

// ---------------- GEMM: C[M,N] = A[M,K] @ B[K,N], fp32, tiled ----------------
template<int BM, int BN, int BK>
__global__ __launch_bounds__(256)
void gemm_kernel(const float* __restrict__ A, const float* __restrict__ B,
                 float* __restrict__ C, int M, int N, int K) {
  __shared__ float As[BK][BM + 4];
  __shared__ float Bs[BK][BN + 4];
  const int bm = blockIdx.x * BM;
  const int bn = blockIdx.y * BN;
  const int tid = threadIdx.x;
  const int tr = (tid / (BN / 4)) * 4;
  const int tc = (tid % (BN / 4)) * 4;
  float acc[4][4] = {};
  for (int k0 = 0; k0 < K; k0 += BK) {
    for (int i = tid; i < BM * BK; i += 256) {
      int r = i / BK, c = i % BK;
      int gr = bm + r;
      As[c][r] = (gr < M) ? A[(size_t)gr * K + k0 + c] : 0.f;
    }
    for (int i = tid; i < BK * BN; i += 256) {
      int r = i / BN, c = i % BN;
      Bs[r][c] = B[(size_t)(k0 + r) * N + bn + c];
    }
    __syncthreads();
#pragma unroll
    for (int k = 0; k < BK; ++k) {
      float a[4], b[4];
#pragma unroll
      for (int i = 0; i < 4; i++) a[i] = As[k][tr + i];
#pragma unroll
      for (int j = 0; j < 4; j++) b[j] = Bs[k][tc + j];
#pragma unroll
      for (int i = 0; i < 4; i++)
#pragma unroll
        for (int j = 0; j < 4; j++) acc[i][j] += a[i] * b[j];
    }
    __syncthreads();
  }
#pragma unroll
  for (int i = 0; i < 4; i++) {
    int r = bm + tr + i;
    if (r < M) {
#pragma unroll
      for (int j = 0; j < 4; j++) C[(size_t)r * N + bn + tc + j] = acc[i][j];
    }
  }
}

// ---------------- per-(node,head) attention halves ----------------
__global__ void node_att_kernel(const float* __restrict__ h,
                                const float* __restrict__ a_src,
                                const float* __restrict__ a_dst,
                                float* __restrict__ al_s, float* __restrict__ al_d,
                                int N) {
  int i = blockIdx.x * blockDim.x + threadIdx.x;  // over N*4
  if (i >= N * 4) return;
  int n = i >> 2, hd = i & 3;
  const float* hp = h + (size_t)n * 128 + hd * 32;
  const float* as = a_src + hd * 32;
  const float* ad = a_dst + hd * 32;
  float ss = 0.f, sd = 0.f;
#pragma unroll
  for (int d = 0; d < 32; ++d) {
    float v = hp[d];
    ss += v * as[d];
    sd += v * ad[d];
  }
  al_s[i] = ss;
  al_d[i] = sd;
}

// ---------------- CSR build: histogram ----------------
__global__ void count_kernel(const int* __restrict__ dst, int* __restrict__ deg, int E) {
  int i = blockIdx.x * blockDim.x + threadIdx.x;
  if (i < E) atomicAdd(&deg[dst[i]], 1);
}

// ---------------- CSR build: single-block exclusive scan (N=50K is tiny) ----
__global__ __launch_bounds__(1024)
void scan_kernel(const int* __restrict__ deg, int* __restrict__ offs,
                 int* __restrict__ cursor, int n) {
  __shared__ int wsum[16];
  __shared__ int carry;
  int t = threadIdx.x, lane = t & 63, wid = t >> 6;
  if (t == 0) carry = 0;
  __syncthreads();
  for (int base = 0; base < n; base += 1024) {
    int i = base + t;
    int v = (i < n) ? deg[i] : 0;
    int sv = v;
#pragma unroll
    for (int dlt = 1; dlt < 64; dlt <<= 1) {
      int u = __shfl_up(sv, dlt);
      if (lane >= dlt) sv += u;
    }
    if (lane == 63) wsum[wid] = sv;
    __syncthreads();
    if (t < 16) {
      int ws = wsum[t];
#pragma unroll
      for (int dlt = 1; dlt < 16; dlt <<= 1) {
        int u = __shfl_up(ws, dlt);
        if (t >= dlt) ws += u;
      }
      wsum[t] = ws;
    }
    __syncthreads();
    int pre = carry + (wid ? wsum[wid - 1] : 0);
    int excl = pre + sv - v;
    if (i < n) { offs[i] = excl; cursor[i] = excl; }
    __syncthreads();
    if (t == 0) carry += wsum[15];
    __syncthreads();
  }
}

// ---------------- CSR build: scatter src ids into dst-sorted order ----------
__global__ void scatter_kernel(const int* __restrict__ src, const int* __restrict__ dst,
                               int* __restrict__ cursor, int* __restrict__ srt, int E) {
  int i = blockIdx.x * blockDim.x + threadIdx.x;
  if (i < E) {
    int p = atomicAdd(&cursor[dst[i]], 1);
    srt[p] = src[i];
  }
}

// ---------------- fused softmax + weighted gather, one block per dst node ---
__global__ __launch_bounds__(128)
void gat_scatter_kernel(const int* __restrict__ srt, const int* __restrict__ offs,
                        const int* __restrict__ deg,
                        const float* __restrict__ h,
                        const float* __restrict__ al_s, const float* __restrict__ al_d,
                        const float* __restrict__ bias,
                        float* __restrict__ out, int rel) {
  const int d = blockIdx.x;
  const int start = offs[d];
  const int dg = deg[d];
  const int t = threadIdx.x;

  __shared__ float denom_s[4];
  __shared__ float w_s[MAXE_LDS * 4];
  __shared__ int   s_s[MAXE_LDS];
  if (t < 4) denom_s[t] = 0.f;
  __syncthreads();

  const bool fits = (dg <= MAXE_LDS);
  // phase 1: denominator (4 heads x 32 edge-slots in parallel)
  {
    int hd = t & 3;
    float ald = al_d[d * 4 + hd];
    float local = 0.f;
    for (int e = t >> 2; e < dg; e += 32) {
      int s = srt[start + e];
      float a = al_s[s * 4 + hd] + ald;
      a = a > 0.f ? a : NEG_SLOPE * a;
      float ex = expf(a);
      local += ex;
      if (fits) { w_s[e * 4 + hd] = ex; if (hd == 0) s_s[e] = s; }
    }
    atomicAdd(&denom_s[hd], local);
  }
  __syncthreads();

  // phase 2: weighted feature accumulation, thread == feature
  const int f = t;
  const int h2 = f >> 5;
  const float rdn = 1.f / (denom_s[h2] + 1e-16f);
  float acc = 0.f;
  if (fits) {
#pragma unroll 4
    for (int e = 0; e < dg; ++e) {
      acc += h[(size_t)s_s[e] * 128 + f] * w_s[e * 4 + h2];
    }
  } else {
    float ald = al_d[d * 4 + h2];
    for (int e = 0; e < dg; ++e) {
      int s = srt[start + e];
      float a = al_s[s * 4 + h2] + ald;
      a = a > 0.f ? a : NEG_SLOPE * a;
      acc += h[(size_t)s * 128 + f] * expf(a);
    }
  }
  acc *= rdn;

  size_t oi = (size_t)d * 128 + f;
  if (rel == 0) out[oi] = acc + bias[f] + bias[128 + f] + bias[256 + f];
  else          out[oi] += acc;
}

extern "C" void kernel_launch(void* const* d_in, const int* in_sizes, int n_in,
                              void* d_out, int out_size, void* d_ws, size_t ws_size,
                              hipStream_t stream) {
  const float* x     = (const float*)d_in[0];
  const int*   ei[3] = {(const int*)d_in[1], (const int*)d_in[2], (const int*)d_in[3]};
  const float* W     = (const float*)d_in[4];
  const float* a_src = (const float*)d_in[5];
  const float* a_dst = (const float*)d_in[6];
  const float* bias  = (const float*)d_in[7];

  const int Fin = 256, Fout = 128, H = 4, D = 32, R = 3;
  const int N = in_sizes[0] / Fin;
  int Emax = 0;
  for (int r = 0; r < R; ++r) { int e = in_sizes[1 + r] / 2; if (e > Emax) Emax = e; }

  float* out = (float*)d_out;

  // ws layout (floats): h[N*128] | al_s[N*4] | al_d[N*4] | then ints:
  // deg[N] | offs[N] | cursor[N] | srt[Emax]
  float* h    = (float*)d_ws;
  float* al_s = h + (size_t)N * Fout;
  float* al_d = al_s + (size_t)N * H;
  int*   deg    = (int*)(al_d + (size_t)N * H);
  int*   offs   = deg + N;
  int*   cursor = offs + N;
  int*   srt    = cursor + N;

  for (int r = 0; r < R; ++r) {
    const int E = in_sizes[1 + r] / 2;
    const int* srcp = ei[r];
    const int* dstp = ei[r] + E;

    // h = x @ W[r]
    dim3 gg((N + 63) / 64, Fout / 64);
    gemm_kernel<64, 64, 16><<<gg, 256, 0, stream>>>(
        x, W + (size_t)r * Fin * Fout, h, N, Fout, Fin);

    // attention halves
    node_att_kernel<<<(N * H + 255) / 256, 256, 0, stream>>>(
        h, a_src + r * H * D, a_dst + r * H * D, al_s, al_d, N);

    // CSR build by dst
    hipMemsetAsync(deg, 0, (size_t)N * sizeof(int), stream);
    count_kernel<<<(E + 255) / 256, 256, 0, stream>>>(dstp, deg, E);
    scan_kernel<<<1, 1024, 0, stream>>>(deg, offs, cursor, N);
    scatter_kernel<<<(E + 255) / 256, 256, 0, stream>>>(srcp, dstp, cursor, srt, E);

    // fused softmax + gather + (bias on r==0), one block per dst row
    gat_scatter_kernel<<<N, 128, 0, stream>>>(
        srt, offs, deg, h, al_s, al_d, bias, out, r);
  }
}

// Round 3
// 539.164 us; speedup vs baseline: 2.6998x; 1.6197x over previous
//
#include <hip/hip_runtime.h>
#include <hip/hip_bf16.h>

#define NEG_SLOPE 0.2f
#define MAXE_LDS 256

typedef short bf16x8 __attribute__((ext_vector_type(8)));
typedef float f32x4 __attribute__((ext_vector_type(4)));

__device__ inline ushort f2bf(float f) {
  __hip_bfloat16 b = __float2bfloat16(f);
  return *(ushort*)&b;
}
__device__ inline float bf2f(ushort u) {
  unsigned int v = ((unsigned int)u) << 16;
  return *(float*)&v;
}

// ---------- prep: WbigT[448][256] bf16 = [W0|W1|W2|Wa_src,Wa_dst|pad]^T -----
__global__ void prep_kernel(const float* __restrict__ W,
                            const float* __restrict__ a_src,
                            const float* __restrict__ a_dst,
                            ushort* __restrict__ WbigT) {
  int i = blockIdx.x * blockDim.x + threadIdx.x;  // over 448*256
  if (i >= 448 * 256) return;
  int c = i >> 8, k = i & 255;
  float v = 0.f;
  if (c < 384) {
    int r = c >> 7, j = c & 127;
    v = W[((size_t)r * 256 + k) * 128 + j];
  } else if (c < 408) {
    int c6 = c - 384, r = c6 >> 3, hh = c6 & 7, hd = hh & 3;
    const float* a = (hh < 4 ? a_src : a_dst) + (r * 4 + hd) * 32;
    const float* wp = W + ((size_t)r * 256 + k) * 128 + hd * 32;
#pragma unroll
    for (int d = 0; d < 32; ++d) v += wp[d] * a[d];
  }
  WbigT[i] = f2bf(v);
}

// ---------- MFMA GEMM: [M,256] x [256,448] -> hall bf16 [M,384] + al fp32 ---
// al layout: [(sd*3+r)*M + node]*4 + head   (sd: 0=src,1=dst)
__global__ __launch_bounds__(256)
void gemm_mfma_kernel(const float* __restrict__ x, const ushort* __restrict__ WT,
                      ushort* __restrict__ hall, float* __restrict__ al, int M) {
  __shared__ __align__(16) ushort As[64][72];
  __shared__ __align__(16) ushort Bs[64][72];
  const int bm = blockIdx.x * 64;
  const int bn = blockIdx.y * 64;
  const int t = threadIdx.x;
  const int l = t & 63;
  const int w = t >> 6;
  const int wm = (w >> 1) * 32, wn = (w & 1) * 32;
  const int lr = l & 15, lg = l >> 4;

  f32x4 zero = {0.f, 0.f, 0.f, 0.f};
  f32x4 acc[2][2];
  acc[0][0] = zero; acc[0][1] = zero; acc[1][0] = zero; acc[1][1] = zero;

  for (int k0 = 0; k0 < 256; k0 += 64) {
    // stage A (fp32 -> bf16 on the fly): 64 rows x 64 k
#pragma unroll
    for (int p = 0; p < 4; ++p) {
      int idx = p * 256 + t;
      int row = idx >> 4, ch = idx & 15;
      int grow = bm + row;
      float4 v = make_float4(0.f, 0.f, 0.f, 0.f);
      if (grow < M) v = *(const float4*)(x + (size_t)grow * 256 + k0 + ch * 4);
      unsigned int p0 = (unsigned int)f2bf(v.x) | ((unsigned int)f2bf(v.y) << 16);
      unsigned int p1 = (unsigned int)f2bf(v.z) | ((unsigned int)f2bf(v.w) << 16);
      *(uint2*)&As[row][ch * 4] = make_uint2(p0, p1);
    }
    // stage B^T (already bf16): 64 cols x 64 k
#pragma unroll
    for (int p = 0; p < 2; ++p) {
      int idx = p * 256 + t;
      int nrow = idx >> 3, ch = idx & 7;
      *(uint4*)&Bs[nrow][ch * 8] =
          *(const uint4*)(WT + ((size_t)(bn + nrow)) * 256 + k0 + ch * 8);
    }
    __syncthreads();
#pragma unroll
    for (int kk = 0; kk < 64; kk += 32) {
      bf16x8 afrag[2], bfrag[2];
#pragma unroll
      for (int i = 0; i < 2; ++i)
        afrag[i] = *(bf16x8*)&As[wm + i * 16 + lr][kk + lg * 8];
#pragma unroll
      for (int j = 0; j < 2; ++j)
        bfrag[j] = *(bf16x8*)&Bs[wn + j * 16 + lr][kk + lg * 8];
#pragma unroll
      for (int i = 0; i < 2; ++i)
#pragma unroll
        for (int j = 0; j < 2; ++j)
          acc[i][j] = __builtin_amdgcn_mfma_f32_16x16x32_bf16(
              afrag[i], bfrag[j], acc[i][j], 0, 0, 0);
    }
    __syncthreads();
  }
  // epilogue: C/D layout col=lane&15, row=(lane>>4)*4+reg
#pragma unroll
  for (int i = 0; i < 2; ++i) {
#pragma unroll
    for (int rr = 0; rr < 4; ++rr) {
      int grow = bm + wm + i * 16 + lg * 4 + rr;
      if (grow >= M) continue;
#pragma unroll
      for (int j = 0; j < 2; ++j) {
        int gcol = bn + wn + j * 16 + lr;
        float c = acc[i][j][rr];
        if (gcol < 384) {
          hall[(size_t)grow * 384 + gcol] = f2bf(c);
        } else if (gcol < 408) {
          int c6 = gcol - 384, r = c6 >> 3, hh = c6 & 7;
          al[(((size_t)(hh < 4 ? 0 : 3) + r) * M + grow) * 4 + (hh & 3)] = c;
        }
      }
    }
  }
}

// ---------- CSR build ----------
__global__ void count_kernel(const int* __restrict__ dst, int* __restrict__ deg, int E) {
  int i = blockIdx.x * blockDim.x + threadIdx.x;
  if (i < E) atomicAdd(&deg[dst[i]], 1);
}

__global__ __launch_bounds__(1024)
void scan1_kernel(const int* __restrict__ deg, int* __restrict__ offs,
                  int* __restrict__ bsum, int n) {
  __shared__ int wsum[16];
  int t = threadIdx.x, lane = t & 63, wid = t >> 6;
  int i = blockIdx.x * 1024 + t;
  int v = (i < n) ? deg[i] : 0;
  int sv = v;
#pragma unroll
  for (int d = 1; d < 64; d <<= 1) {
    int u = __shfl_up(sv, d);
    if (lane >= d) sv += u;
  }
  if (lane == 63) wsum[wid] = sv;
  __syncthreads();
  if (t < 16) {
    int ws = wsum[t];
#pragma unroll
    for (int d = 1; d < 16; d <<= 1) {
      int u = __shfl_up(ws, d);
      if (t >= d) ws += u;
    }
    wsum[t] = ws;
  }
  __syncthreads();
  int excl = (wid ? wsum[wid - 1] : 0) + sv - v;
  if (i < n) offs[i] = excl;
  if (t == 0) bsum[blockIdx.x] = wsum[15];
}

__global__ void scan2_kernel(int* __restrict__ bsum, int nb) {
  int t = threadIdx.x;  // 64 threads, nb <= 64
  int v = (t < nb) ? bsum[t] : 0;
  int sv = v;
#pragma unroll
  for (int d = 1; d < 64; d <<= 1) {
    int u = __shfl_up(sv, d);
    if (t >= d) sv += u;
  }
  if (t < nb) bsum[t] = sv - v;
}

__global__ void scan3_kernel(int* __restrict__ offs, int* __restrict__ cursor,
                             const int* __restrict__ bsum, int n) {
  int i = blockIdx.x * blockDim.x + threadIdx.x;
  if (i < n) {
    int o = offs[i] + bsum[i >> 10];
    offs[i] = o;
    cursor[i] = o;
  }
}

__global__ void scatter_kernel(const int* __restrict__ src, const int* __restrict__ dst,
                               int* __restrict__ cursor, int* __restrict__ srt, int E) {
  int i = blockIdx.x * blockDim.x + threadIdx.x;
  if (i < E) {
    int p = atomicAdd(&cursor[dst[i]], 1);
    srt[p] = src[i];
  }
}

// ---------- fused softmax + weighted gather, one block per dst node ----------
__global__ __launch_bounds__(128)
void gat_scatter_kernel(const int* __restrict__ srt, const int* __restrict__ offs,
                        const int* __restrict__ deg,
                        const ushort* __restrict__ hall,
                        const float* __restrict__ alS, const float* __restrict__ alD,
                        const float* __restrict__ bias,
                        float* __restrict__ out, int rel) {
  const int d = blockIdx.x;
  const int start = offs[d];
  const int dg = deg[d];
  const int t = threadIdx.x;

  __shared__ float denom_s[4];
  __shared__ float w_s[MAXE_LDS * 4];
  __shared__ int s_s[MAXE_LDS];
  if (t < 4) denom_s[t] = 0.f;
  __syncthreads();

  const bool fits = (dg <= MAXE_LDS);
  {
    int hd = t & 3;
    float ald = alD[(size_t)d * 4 + hd];
    float local = 0.f;
    for (int e = t >> 2; e < dg; e += 32) {
      int s = srt[start + e];
      float a = alS[(size_t)s * 4 + hd] + ald;
      a = a > 0.f ? a : NEG_SLOPE * a;
      float ex = __expf(a);
      local += ex;
      if (fits) {
        w_s[e * 4 + hd] = ex;
        if (hd == 0) s_s[e] = s;
      }
    }
    atomicAdd(&denom_s[hd], local);
  }
  __syncthreads();

  const int f = t;
  const int h2 = f >> 5;
  const float rdn = 1.f / (denom_s[h2] + 1e-16f);
  float acc = 0.f;
  if (fits) {
#pragma unroll 4
    for (int e = 0; e < dg; ++e) {
      acc += bf2f(hall[(size_t)s_s[e] * 384 + rel * 128 + f]) * w_s[e * 4 + h2];
    }
  } else {
    float ald = alD[(size_t)d * 4 + h2];
    for (int e = 0; e < dg; ++e) {
      int s = srt[start + e];
      float a = alS[(size_t)s * 4 + h2] + ald;
      a = a > 0.f ? a : NEG_SLOPE * a;
      acc += bf2f(hall[(size_t)s * 384 + rel * 128 + f]) * __expf(a);
    }
  }
  acc *= rdn;

  size_t oi = (size_t)d * 128 + f;
  if (rel == 0) out[oi] = acc + bias[f] + bias[128 + f] + bias[256 + f];
  else          out[oi] += acc;
}

extern "C" void kernel_launch(void* const* d_in, const int* in_sizes, int n_in,
                              void* d_out, int out_size, void* d_ws, size_t ws_size,
                              hipStream_t stream) {
  const float* x     = (const float*)d_in[0];
  const int*   ei[3] = {(const int*)d_in[1], (const int*)d_in[2], (const int*)d_in[3]};
  const float* W     = (const float*)d_in[4];
  const float* a_src = (const float*)d_in[5];
  const float* a_dst = (const float*)d_in[6];
  const float* bias  = (const float*)d_in[7];

  const int Fin = 256, R = 3;
  const int N = in_sizes[0] / Fin;
  int Emax = 0;
  for (int r = 0; r < R; ++r) { int e = in_sizes[1 + r] / 2; if (e > Emax) Emax = e; }

  float* out = (float*)d_out;

  // ws layout
  char* p = (char*)d_ws;
  ushort* WbigT = (ushort*)p;        p += (size_t)448 * 256 * 2;
  ushort* hall  = (ushort*)p;        p += (size_t)N * 384 * 2;
  float*  al    = (float*)p;         p += (size_t)6 * N * 4 * 4;
  int*    deg    = (int*)p;          p += (size_t)N * 4;
  int*    offs   = (int*)p;          p += (size_t)N * 4;
  int*    cursor = (int*)p;          p += (size_t)N * 4;
  int*    bsum   = (int*)p;          p += 256;
  int*    srt    = (int*)p;          p += (size_t)Emax * 4;

  // prep combined weight matrix (bf16, transposed)
  prep_kernel<<<(448 * 256 + 255) / 256, 256, 0, stream>>>(W, a_src, a_dst, WbigT);

  // one MFMA GEMM for all relations + attention projections
  dim3 gg((N + 63) / 64, 7);
  gemm_mfma_kernel<<<gg, 256, 0, stream>>>(x, WbigT, hall, al, N);

  const int nb1 = (N + 1023) / 1024;
  for (int r = 0; r < R; ++r) {
    const int E = in_sizes[1 + r] / 2;
    const int* srcp = ei[r];
    const int* dstp = ei[r] + E;

    hipMemsetAsync(deg, 0, (size_t)N * sizeof(int), stream);
    count_kernel<<<(E + 255) / 256, 256, 0, stream>>>(dstp, deg, E);
    scan1_kernel<<<nb1, 1024, 0, stream>>>(deg, offs, bsum, N);
    scan2_kernel<<<1, 64, 0, stream>>>(bsum, nb1);
    scan3_kernel<<<(N + 1023) / 1024, 1024, 0, stream>>>(offs, cursor, bsum, N);
    scatter_kernel<<<(E + 255) / 256, 256, 0, stream>>>(srcp, dstp, cursor, srt, E);

    const float* alS = al + (size_t)(0 + r) * N * 4;
    const float* alD = al + (size_t)(3 + r) * N * 4;
    gat_scatter_kernel<<<N, 128, 0, stream>>>(
        srt, offs, deg, hall, alS, alD, bias, out, r);
  }
}

// Round 4
// 524.312 us; speedup vs baseline: 2.7763x; 1.0283x over previous
//
#include <hip/hip_runtime.h>
#include <hip/hip_bf16.h>

#define NEG_SLOPE 0.2f
#define MAXE_LDS 256

typedef short bf16x8 __attribute__((ext_vector_type(8)));
typedef float f32x4 __attribute__((ext_vector_type(4)));

__device__ inline ushort f2bf(float f) {
  __hip_bfloat16 b = __float2bfloat16(f);
  return *(ushort*)&b;
}
__device__ inline float bf2f(ushort u) {
  unsigned int v = ((unsigned int)u) << 16;
  return *(float*)&v;
}

// ---------- prep: WbigT[448][256] bf16 = [W0|W1|W2|Wa_src,Wa_dst|pad]^T -----
__global__ void prep_kernel(const float* __restrict__ W,
                            const float* __restrict__ a_src,
                            const float* __restrict__ a_dst,
                            ushort* __restrict__ WbigT) {
  int i = blockIdx.x * blockDim.x + threadIdx.x;  // over 448*256
  if (i >= 448 * 256) return;
  int c = i >> 8, k = i & 255;
  float v = 0.f;
  if (c < 384) {
    int r = c >> 7, j = c & 127;
    v = W[((size_t)r * 256 + k) * 128 + j];
  } else if (c < 408) {
    int c6 = c - 384, r = c6 >> 3, hh = c6 & 7, hd = hh & 3;
    const float* a = (hh < 4 ? a_src : a_dst) + (r * 4 + hd) * 32;
    const float* wp = W + ((size_t)r * 256 + k) * 128 + hd * 32;
#pragma unroll
    for (int d = 0; d < 32; ++d) v += wp[d] * a[d];
  }
  WbigT[i] = f2bf(v);
}

// ---------- MFMA GEMM: [M,256] x [256,448], block owns 64 rows x ALL 448 cols
// al layout: [(sd*3+r)*M + node]*4 + head   (sd: 0=src,1=dst)
__global__ __launch_bounds__(256, 2)
void gemm_mfma_kernel(const float* __restrict__ x, const ushort* __restrict__ WT,
                      ushort* __restrict__ hall, float* __restrict__ al, int M) {
  __shared__ __align__(16) ushort As[64][40];
  __shared__ __align__(16) ushort Bs[448][40];
  const int bm = blockIdx.x * 64;
  const int t = threadIdx.x;
  const int l = t & 63;
  const int w = t >> 6;
  const int wm = (w >> 1) * 32;        // wave row offset (0/32)
  const int wn = (w & 1) * 224;        // wave col offset (0/224)
  const int lr = l & 15, lg = l >> 4;

  f32x4 acc[2][14];
#pragma unroll
  for (int i = 0; i < 2; ++i)
#pragma unroll
    for (int j = 0; j < 14; ++j) acc[i][j] = (f32x4){0.f, 0.f, 0.f, 0.f};

  for (int k0 = 0; k0 < 256; k0 += 32) {
    // stage A: 64 rows x 32 k, fp32 -> bf16 (each thread: 8 floats)
    {
      int row = t >> 2, seg = t & 3;
      int grow = bm + row;
      float4 v0 = make_float4(0.f, 0.f, 0.f, 0.f), v1 = v0;
      if (grow < M) {
        const float* xp = x + (size_t)grow * 256 + k0 + seg * 8;
        v0 = *(const float4*)xp;
        v1 = *(const float4*)(xp + 4);
      }
      uint4 pk;
      pk.x = (unsigned)f2bf(v0.x) | ((unsigned)f2bf(v0.y) << 16);
      pk.y = (unsigned)f2bf(v0.z) | ((unsigned)f2bf(v0.w) << 16);
      pk.z = (unsigned)f2bf(v1.x) | ((unsigned)f2bf(v1.y) << 16);
      pk.w = (unsigned)f2bf(v1.z) | ((unsigned)f2bf(v1.w) << 16);
      *(uint4*)&As[row][seg * 8] = pk;
    }
    // stage B: 448 cols x 32 k bf16 (7 x 256 threads x 16B)
#pragma unroll
    for (int p = 0; p < 7; ++p) {
      int idx = p * 256 + t;           // 0..1791
      int nrow = idx >> 2, ch = idx & 3;
      *(uint4*)&Bs[nrow][ch * 8] =
          *(const uint4*)(WT + (size_t)nrow * 256 + k0 + ch * 8);
    }
    __syncthreads();

    bf16x8 afrag[2];
    afrag[0] = *(bf16x8*)&As[wm + lr][lg * 8];
    afrag[1] = *(bf16x8*)&As[wm + 16 + lr][lg * 8];
#pragma unroll
    for (int j = 0; j < 14; ++j) {
      bf16x8 bfrag = *(bf16x8*)&Bs[wn + j * 16 + lr][lg * 8];
      acc[0][j] = __builtin_amdgcn_mfma_f32_16x16x32_bf16(afrag[0], bfrag, acc[0][j], 0, 0, 0);
      acc[1][j] = __builtin_amdgcn_mfma_f32_16x16x32_bf16(afrag[1], bfrag, acc[1][j], 0, 0, 0);
    }
    __syncthreads();
  }

  // epilogue: C/D layout col=lane&15, row=(lane>>4)*4+reg
#pragma unroll
  for (int i = 0; i < 2; ++i) {
#pragma unroll
    for (int rr = 0; rr < 4; ++rr) {
      int grow = bm + wm + i * 16 + lg * 4 + rr;
      if (grow >= M) continue;
#pragma unroll
      for (int j = 0; j < 14; ++j) {
        int gcol = wn + j * 16 + lr;
        float c = acc[i][j][rr];
        if (gcol < 384) {
          hall[(size_t)grow * 384 + gcol] = f2bf(c);
        } else if (gcol < 408) {
          int c6 = gcol - 384, r = c6 >> 3, hh = c6 & 7;
          al[(((size_t)(hh < 4 ? 0 : 3) + r) * M + grow) * 4 + (hh & 3)] = c;
        }
      }
    }
  }
}

// ---------- CSR build (all 3 relations in one pass) ----------
__global__ void count3_kernel(const int* __restrict__ d0, const int* __restrict__ d1,
                              const int* __restrict__ d2, int E0, int E1, int E2,
                              int* __restrict__ deg, int N) {
  int i = blockIdx.x * blockDim.x + threadIdx.x;
  int rel, e;
  const int* dp;
  if (i < E0)           { rel = 0; e = i;           dp = d0; }
  else if (i < E0 + E1) { rel = 1; e = i - E0;      dp = d1; }
  else if (i < E0 + E1 + E2) { rel = 2; e = i - E0 - E1; dp = d2; }
  else return;
  atomicAdd(&deg[rel * N + dp[e]], 1);
}

__global__ __launch_bounds__(1024)
void scan1_kernel(const int* __restrict__ deg, int* __restrict__ offs,
                  int* __restrict__ bsum, int n) {
  __shared__ int wsum[16];
  int t = threadIdx.x, lane = t & 63, wid = t >> 6;
  int i = blockIdx.x * 1024 + t;
  int v = (i < n) ? deg[i] : 0;
  int sv = v;
#pragma unroll
  for (int d = 1; d < 64; d <<= 1) {
    int u = __shfl_up(sv, d);
    if (lane >= d) sv += u;
  }
  if (lane == 63) wsum[wid] = sv;
  __syncthreads();
  if (t < 16) {
    int ws = wsum[t];
#pragma unroll
    for (int d = 1; d < 16; d <<= 1) {
      int u = __shfl_up(ws, d);
      if (t >= d) ws += u;
    }
    wsum[t] = ws;
  }
  __syncthreads();
  int excl = (wid ? wsum[wid - 1] : 0) + sv - v;
  if (i < n) offs[i] = excl;
  if (t == 0) bsum[blockIdx.x] = wsum[15];
}

// single block, 256 threads, handles up to 256 block sums (3N <= 262144)
__global__ __launch_bounds__(256)
void scan2_kernel(int* __restrict__ bsum, int nb) {
  __shared__ int tmp[256];
  int t = threadIdx.x;
  int v = (t < nb) ? bsum[t] : 0;
  tmp[t] = v;
  __syncthreads();
#pragma unroll
  for (int d = 1; d < 256; d <<= 1) {
    int u = (t >= d) ? tmp[t - d] : 0;
    __syncthreads();
    tmp[t] += u;
    __syncthreads();
  }
  if (t < nb) bsum[t] = tmp[t] - v;  // exclusive
}

__global__ void scan3_kernel(int* __restrict__ offs, int* __restrict__ cursor,
                             const int* __restrict__ bsum, int n) {
  int i = blockIdx.x * blockDim.x + threadIdx.x;
  if (i < n) {
    int o = offs[i] + bsum[i >> 10];
    offs[i] = o;
    cursor[i] = o;
  }
}

__global__ void scatter3_kernel(const int* __restrict__ s0, const int* __restrict__ d0,
                                const int* __restrict__ s1, const int* __restrict__ d1,
                                const int* __restrict__ s2, const int* __restrict__ d2,
                                int E0, int E1, int E2,
                                int* __restrict__ cursor, int* __restrict__ srt, int N) {
  int i = blockIdx.x * blockDim.x + threadIdx.x;
  int rel, e;
  const int *sp, *dp;
  if (i < E0)           { rel = 0; e = i;           sp = s0; dp = d0; }
  else if (i < E0 + E1) { rel = 1; e = i - E0;      sp = s1; dp = d1; }
  else if (i < E0 + E1 + E2) { rel = 2; e = i - E0 - E1; sp = s2; dp = d2; }
  else return;
  int p = atomicAdd(&cursor[rel * N + dp[e]], 1);
  srt[p] = sp[e];
}

// ---------- fused softmax + gather over ALL relations, one block per dst ----
__global__ __launch_bounds__(128)
void gat_fused_kernel(const int* __restrict__ srt, const int* __restrict__ offs,
                      const int* __restrict__ deg,
                      const ushort* __restrict__ hall,
                      const float* __restrict__ al,
                      const float* __restrict__ bias,
                      float* __restrict__ out, int N) {
  const int d = blockIdx.x;
  const int t = threadIdx.x;
  const int f = t, h2 = f >> 5;

  __shared__ float denom_s[4];
  __shared__ float w_s[MAXE_LDS * 4];
  __shared__ int s_s[MAXE_LDS];

  float acc = 0.f;
#pragma unroll
  for (int rel = 0; rel < 3; ++rel) {
    const int start = offs[rel * N + d];
    const int dg = deg[rel * N + d];
    const float* alS = al + (size_t)rel * N * 4;
    const float* alD = al + (size_t)(3 + rel) * N * 4;
    if (t < 4) denom_s[t] = 0.f;
    __syncthreads();
    const bool fits = (dg <= MAXE_LDS);
    {
      int hd = t & 3;
      float ald = alD[(size_t)d * 4 + hd];
      float local = 0.f;
      for (int e = t >> 2; e < dg; e += 32) {
        int s = srt[start + e];
        float a = alS[(size_t)s * 4 + hd] + ald;
        a = a > 0.f ? a : NEG_SLOPE * a;
        float ex = __expf(a);
        local += ex;
        if (fits) {
          w_s[e * 4 + hd] = ex;
          if (hd == 0) s_s[e] = s;
        }
      }
      atomicAdd(&denom_s[hd], local);
    }
    __syncthreads();
    float rdn = 1.f / (denom_s[h2] + 1e-16f);
    float a2 = 0.f;
    if (fits) {
#pragma unroll 4
      for (int e = 0; e < dg; ++e) {
        a2 += bf2f(hall[(size_t)s_s[e] * 384 + rel * 128 + f]) * w_s[e * 4 + h2];
      }
    } else {
      float ald = alD[(size_t)d * 4 + h2];
      for (int e = 0; e < dg; ++e) {
        int s = srt[start + e];
        float a = alS[(size_t)s * 4 + h2] + ald;
        a = a > 0.f ? a : NEG_SLOPE * a;
        a2 += bf2f(hall[(size_t)s * 384 + rel * 128 + f]) * __expf(a);
      }
    }
    acc += a2 * rdn;
    __syncthreads();  // protect denom_s/w_s reuse in next relation
  }
  out[(size_t)d * 128 + f] = acc + bias[f] + bias[128 + f] + bias[256 + f];
}

extern "C" void kernel_launch(void* const* d_in, const int* in_sizes, int n_in,
                              void* d_out, int out_size, void* d_ws, size_t ws_size,
                              hipStream_t stream) {
  const float* x     = (const float*)d_in[0];
  const int*   ei[3] = {(const int*)d_in[1], (const int*)d_in[2], (const int*)d_in[3]};
  const float* W     = (const float*)d_in[4];
  const float* a_src = (const float*)d_in[5];
  const float* a_dst = (const float*)d_in[6];
  const float* bias  = (const float*)d_in[7];

  const int Fin = 256;
  const int N = in_sizes[0] / Fin;
  const int E0 = in_sizes[1] / 2, E1 = in_sizes[2] / 2, E2 = in_sizes[3] / 2;
  const int Etot = E0 + E1 + E2;

  float* out = (float*)d_out;

  // ws layout
  char* p = (char*)d_ws;
  ushort* WbigT  = (ushort*)p;  p += (size_t)448 * 256 * 2;
  ushort* hall   = (ushort*)p;  p += (size_t)N * 384 * 2;
  float*  al     = (float*)p;   p += (size_t)6 * N * 4 * 4;
  int*    deg    = (int*)p;     p += (size_t)3 * N * 4;
  int*    offs   = (int*)p;     p += (size_t)3 * N * 4;
  int*    cursor = (int*)p;     p += (size_t)3 * N * 4;
  int*    bsum   = (int*)p;     p += 256 * 4;
  int*    srt    = (int*)p;     p += (size_t)Etot * 4;

  // prep combined weight matrix (bf16, transposed)
  prep_kernel<<<(448 * 256 + 255) / 256, 256, 0, stream>>>(W, a_src, a_dst, WbigT);

  // one MFMA GEMM for all relations + attention projections
  gemm_mfma_kernel<<<(N + 63) / 64, 256, 0, stream>>>(x, WbigT, hall, al, N);

  // merged CSR build for all 3 relations
  const int n3 = 3 * N;
  const int nb1 = (n3 + 1023) / 1024;
  hipMemsetAsync(deg, 0, (size_t)n3 * sizeof(int), stream);
  count3_kernel<<<(Etot + 255) / 256, 256, 0, stream>>>(
      ei[0] + E0, ei[1] + E1, ei[2] + E2, E0, E1, E2, deg, N);
  scan1_kernel<<<nb1, 1024, 0, stream>>>(deg, offs, bsum, n3);
  scan2_kernel<<<1, 256, 0, stream>>>(bsum, nb1);
  scan3_kernel<<<(n3 + 1023) / 1024, 1024, 0, stream>>>(offs, cursor, bsum, n3);
  scatter3_kernel<<<(Etot + 255) / 256, 256, 0, stream>>>(
      ei[0], ei[0] + E0, ei[1], ei[1] + E1, ei[2], ei[2] + E2,
      E0, E1, E2, cursor, srt, N);

  // fused softmax + gather + bias, one block per dst row, all relations
  gat_fused_kernel<<<N, 128, 0, stream>>>(srt, offs, deg, hall, al, bias, out, N);
}

// Round 5
// 460.002 us; speedup vs baseline: 3.1644x; 1.1398x over previous
//
#include <hip/hip_runtime.h>
#include <hip/hip_bf16.h>

#define NEG_SLOPE 0.2f
#define MAXE_LDS 256
#define NBMAX 256          // max buckets (3N/1024); N=50000 -> 147

typedef short bf16x8 __attribute__((ext_vector_type(8)));
typedef float f32x4 __attribute__((ext_vector_type(4)));

__device__ inline ushort f2bf(float f) {
  __hip_bfloat16 b = __float2bfloat16(f);
  return *(ushort*)&b;
}
__device__ inline float bf2f(ushort u) {
  unsigned int v = ((unsigned int)u) << 16;
  return *(float*)&v;
}

// ---------- prep: WbigT[448][256] bf16 = [W0|W1|W2|Wa_src,Wa_dst|pad]^T -----
__global__ void prep_kernel(const float* __restrict__ W,
                            const float* __restrict__ a_src,
                            const float* __restrict__ a_dst,
                            ushort* __restrict__ WbigT) {
  int i = blockIdx.x * blockDim.x + threadIdx.x;  // over 448*256
  if (i >= 448 * 256) return;
  int c = i >> 8, k = i & 255;
  float v = 0.f;
  if (c < 384) {
    int r = c >> 7, j = c & 127;
    v = W[((size_t)r * 256 + k) * 128 + j];
  } else if (c < 408) {
    int c6 = c - 384, r = c6 >> 3, hh = c6 & 7, hd = hh & 3;
    const float* a = (hh < 4 ? a_src : a_dst) + (r * 4 + hd) * 32;
    const float* wp = W + ((size_t)r * 256 + k) * 128 + hd * 32;
#pragma unroll
    for (int d = 0; d < 32; ++d) v += wp[d] * a[d];
  }
  WbigT[i] = f2bf(v);
}

// ---------- MFMA GEMM: [M,256] x [256,448], block owns 64 rows x ALL 448 cols
__global__ __launch_bounds__(256, 2)
void gemm_mfma_kernel(const float* __restrict__ x, const ushort* __restrict__ WT,
                      ushort* __restrict__ hall, float* __restrict__ al, int M) {
  __shared__ __align__(16) ushort As[64][40];
  __shared__ __align__(16) ushort Bs[448][40];
  const int bm = blockIdx.x * 64;
  const int t = threadIdx.x;
  const int l = t & 63;
  const int w = t >> 6;
  const int wm = (w >> 1) * 32;
  const int wn = (w & 1) * 224;
  const int lr = l & 15, lg = l >> 4;

  f32x4 acc[2][14];
#pragma unroll
  for (int i = 0; i < 2; ++i)
#pragma unroll
    for (int j = 0; j < 14; ++j) acc[i][j] = (f32x4){0.f, 0.f, 0.f, 0.f};

  for (int k0 = 0; k0 < 256; k0 += 32) {
    {
      int row = t >> 2, seg = t & 3;
      int grow = bm + row;
      float4 v0 = make_float4(0.f, 0.f, 0.f, 0.f), v1 = v0;
      if (grow < M) {
        const float* xp = x + (size_t)grow * 256 + k0 + seg * 8;
        v0 = *(const float4*)xp;
        v1 = *(const float4*)(xp + 4);
      }
      uint4 pk;
      pk.x = (unsigned)f2bf(v0.x) | ((unsigned)f2bf(v0.y) << 16);
      pk.y = (unsigned)f2bf(v0.z) | ((unsigned)f2bf(v0.w) << 16);
      pk.z = (unsigned)f2bf(v1.x) | ((unsigned)f2bf(v1.y) << 16);
      pk.w = (unsigned)f2bf(v1.z) | ((unsigned)f2bf(v1.w) << 16);
      *(uint4*)&As[row][seg * 8] = pk;
    }
#pragma unroll
    for (int p = 0; p < 7; ++p) {
      int idx = p * 256 + t;
      int nrow = idx >> 2, ch = idx & 3;
      *(uint4*)&Bs[nrow][ch * 8] =
          *(const uint4*)(WT + (size_t)nrow * 256 + k0 + ch * 8);
    }
    __syncthreads();

    bf16x8 afrag[2];
    afrag[0] = *(bf16x8*)&As[wm + lr][lg * 8];
    afrag[1] = *(bf16x8*)&As[wm + 16 + lr][lg * 8];
#pragma unroll
    for (int j = 0; j < 14; ++j) {
      bf16x8 bfrag = *(bf16x8*)&Bs[wn + j * 16 + lr][lg * 8];
      acc[0][j] = __builtin_amdgcn_mfma_f32_16x16x32_bf16(afrag[0], bfrag, acc[0][j], 0, 0, 0);
      acc[1][j] = __builtin_amdgcn_mfma_f32_16x16x32_bf16(afrag[1], bfrag, acc[1][j], 0, 0, 0);
    }
    __syncthreads();
  }

#pragma unroll
  for (int i = 0; i < 2; ++i) {
#pragma unroll
    for (int rr = 0; rr < 4; ++rr) {
      int grow = bm + wm + i * 16 + lg * 4 + rr;
      if (grow >= M) continue;
#pragma unroll
      for (int j = 0; j < 14; ++j) {
        int gcol = wn + j * 16 + lr;
        float c = acc[i][j][rr];
        if (gcol < 384) {
          hall[(size_t)grow * 384 + gcol] = f2bf(c);
        } else if (gcol < 408) {
          int c6 = gcol - 384, r = c6 >> 3, hh = c6 & 7;
          al[(((size_t)(hh < 4 ? 0 : 3) + r) * M + grow) * 4 + (hh & 3)] = c;
        }
      }
    }
  }
}

// ---------- edge decode helper ----------
__device__ inline void edge_decode(int i, int E0, int E1,
                                   const int* __restrict__ s0, const int* __restrict__ d0,
                                   const int* __restrict__ s1, const int* __restrict__ d1,
                                   const int* __restrict__ s2, const int* __restrict__ d2,
                                   int N, int& src, int& key) {
  if (i < E0)            { src = s0[i];            key = d0[i]; }
  else if (i < E0 + E1)  { src = s1[i - E0];       key = N + d1[i - E0]; }
  else                   { src = s2[i - E0 - E1];  key = 2 * N + d2[i - E0 - E1]; }
}

// ---------- bucket_count: per-node deg + per-bucket histogram ----------
__global__ __launch_bounds__(256)
void bucket_count(const int* __restrict__ d0, const int* __restrict__ d1,
                  const int* __restrict__ d2, int E0, int E1, int E2,
                  int* __restrict__ deg, int* __restrict__ bhist, int N, int NB) {
  __shared__ int lh[NBMAX];
  int t = threadIdx.x;
  for (int b = t; b < NB; b += 256) lh[b] = 0;
  __syncthreads();
  int Etot = E0 + E1 + E2;
  for (int i = blockIdx.x * 256 + t; i < Etot; i += gridDim.x * 256) {
    int key;
    if (i < E0)           key = d0[i];
    else if (i < E0 + E1) key = N + d1[i - E0];
    else                  key = 2 * N + d2[i - E0 - E1];
    atomicAdd(&deg[key], 1);
    atomicAdd(&lh[key >> 10], 1);
  }
  __syncthreads();
  for (int b = t; b < NB; b += 256) {
    int v = lh[b];
    if (v) atomicAdd(&bhist[b], v);
  }
}

// ---------- bucket_scan: exclusive scan over NB<=256 buckets ----------
__global__ __launch_bounds__(256)
void bucket_scan(const int* __restrict__ bhist, int* __restrict__ boffs,
                 int* __restrict__ bcur, int nb, int etot) {
  __shared__ int tmp[256];
  int t = threadIdx.x;
  int v = (t < nb) ? bhist[t] : 0;
  tmp[t] = v;
  __syncthreads();
#pragma unroll
  for (int d = 1; d < 256; d <<= 1) {
    int u = (t >= d) ? tmp[t - d] : 0;
    __syncthreads();
    tmp[t] += u;
    __syncthreads();
  }
  int excl = tmp[t] - v;
  if (t < nb) { boffs[t] = excl; bcur[t] = excl; }
  if (t == 0) boffs[nb] = etot;
}

// ---------- node-level scans (3N) ----------
__global__ __launch_bounds__(1024)
void scan1_kernel(const int* __restrict__ deg, int* __restrict__ offs,
                  int* __restrict__ bsum, int n) {
  __shared__ int wsum[16];
  int t = threadIdx.x, lane = t & 63, wid = t >> 6;
  int i = blockIdx.x * 1024 + t;
  int v = (i < n) ? deg[i] : 0;
  int sv = v;
#pragma unroll
  for (int d = 1; d < 64; d <<= 1) {
    int u = __shfl_up(sv, d);
    if (lane >= d) sv += u;
  }
  if (lane == 63) wsum[wid] = sv;
  __syncthreads();
  if (t < 16) {
    int ws = wsum[t];
#pragma unroll
    for (int d = 1; d < 16; d <<= 1) {
      int u = __shfl_up(ws, d);
      if (t >= d) ws += u;
    }
    wsum[t] = ws;
  }
  __syncthreads();
  int excl = (wid ? wsum[wid - 1] : 0) + sv - v;
  if (i < n) offs[i] = excl;
  if (t == 0) bsum[blockIdx.x] = wsum[15];
}

__global__ __launch_bounds__(256)
void scan2_kernel(int* __restrict__ bsum, int nb) {
  __shared__ int tmp[256];
  int t = threadIdx.x;
  int v = (t < nb) ? bsum[t] : 0;
  tmp[t] = v;
  __syncthreads();
#pragma unroll
  for (int d = 1; d < 256; d <<= 1) {
    int u = (t >= d) ? tmp[t - d] : 0;
    __syncthreads();
    tmp[t] += u;
    __syncthreads();
  }
  if (t < nb) bsum[t] = tmp[t] - v;
}

__global__ void scan3_kernel(int* __restrict__ offs, int* __restrict__ cursor,
                             const int* __restrict__ bsum, int n) {
  int i = blockIdx.x * blockDim.x + threadIdx.x;
  if (i < n) {
    int o = offs[i] + bsum[i >> 10];
    offs[i] = o;
    cursor[i] = o;
  }
}

// ---------- bucket_stage: group edges by 1024-node bucket into staging ----
__global__ __launch_bounds__(256)
void bucket_stage(const int* __restrict__ s0, const int* __restrict__ d0,
                  const int* __restrict__ s1, const int* __restrict__ d1,
                  const int* __restrict__ s2, const int* __restrict__ d2,
                  int E0, int E1, int E2,
                  int* __restrict__ bcur, uint2* __restrict__ staging,
                  int N, int NB) {
  __shared__ int lh[NBMAX];
  __shared__ int lb[NBMAX];
  int t = threadIdx.x;
  int Etot = E0 + E1 + E2;
  int per = (Etot + gridDim.x - 1) / gridDim.x;
  int lo = blockIdx.x * per;
  int hi = min(lo + per, Etot);
  for (int b = t; b < NB; b += 256) lh[b] = 0;
  __syncthreads();
  for (int i = lo + t; i < hi; i += 256) {
    int key;
    if (i < E0)           key = d0[i];
    else if (i < E0 + E1) key = N + d1[i - E0];
    else                  key = 2 * N + d2[i - E0 - E1];
    atomicAdd(&lh[key >> 10], 1);
  }
  __syncthreads();
  for (int b = t; b < NB; b += 256) {
    int v = lh[b];
    lb[b] = v ? atomicAdd(&bcur[b], v) : 0;
    lh[b] = 0;
  }
  __syncthreads();
  for (int i = lo + t; i < hi; i += 256) {
    int src, key;
    edge_decode(i, E0, E1, s0, d0, s1, d1, s2, d2, N, src, key);
    int b = key >> 10;
    int pos = lb[b] + atomicAdd(&lh[b], 1);
    staging[pos] = make_uint2((unsigned)src, (unsigned)key);
  }
}

// ---------- bucket_scatter: one block per bucket, L2-local scatter ----------
__global__ __launch_bounds__(256)
void bucket_scatter(const uint2* __restrict__ staging, const int* __restrict__ boffs,
                    int* __restrict__ cursor, int* __restrict__ srt) {
  int b = blockIdx.x;
  int lo = boffs[b], hi = boffs[b + 1];
  for (int i = lo + threadIdx.x; i < hi; i += 256) {
    uint2 se = staging[i];
    int p = atomicAdd(&cursor[se.y], 1);
    srt[p] = (int)se.x;
  }
}

// ---------- fused softmax + gather over ALL relations, one block per dst ----
__global__ __launch_bounds__(128)
void gat_fused_kernel(const int* __restrict__ srt, const int* __restrict__ offs,
                      const int* __restrict__ deg,
                      const ushort* __restrict__ hall,
                      const float* __restrict__ al,
                      const float* __restrict__ bias,
                      float* __restrict__ out, int N) {
  const int d = blockIdx.x;
  const int t = threadIdx.x;
  const int half = t >> 6;       // which edge-parity this thread handles
  const int lt = t & 63;
  const int f2 = lt * 2;         // feature pair (f2, f2+1), same head
  const int h2 = lt >> 4;        // head = f2>>5

  __shared__ float denom_s[4];
  __shared__ float w_s[MAXE_LDS * 4];
  __shared__ int s_s[MAXE_LDS];

  float acc0 = 0.f, acc1 = 0.f;
#pragma unroll
  for (int rel = 0; rel < 3; ++rel) {
    const int key = rel * N + d;
    const int start = offs[key];
    const int dg = deg[key];
    const float* alS = al + (size_t)rel * N * 4;
    const float* alD = al + (size_t)(3 + rel) * N * 4;
    if (t < 4) denom_s[t] = 0.f;
    __syncthreads();
    const bool fits = (dg <= MAXE_LDS);
    // phase 1: softmax denominator; 32 edge-slots x 4 heads
    {
      int hd = t & 3;
      float ald = alD[(size_t)d * 4 + hd];
      float local = 0.f;
      for (int e = t >> 2; e < dg; e += 32) {
        int s = srt[start + e];
        float a = alS[(size_t)s * 4 + hd] + ald;
        a = a > 0.f ? a : NEG_SLOPE * a;
        float ex = __expf(a);
        local += ex;
        if (fits) {
          w_s[e * 4 + hd] = ex;
          if (hd == 0) s_s[e] = s;
        }
      }
      atomicAdd(&denom_s[hd], local);
    }
    __syncthreads();
    float rdn = 1.f / (denom_s[h2] + 1e-16f);
    float r0 = 0.f, r1 = 0.f;
    if (fits) {
#pragma unroll 2
      for (int e = half; e < dg; e += 2) {
        int s = s_s[e];
        float w = w_s[e * 4 + h2];
        unsigned u = *(const unsigned*)(hall + (size_t)s * 384 + rel * 128 + f2);
        r0 += bf2f((ushort)(u & 0xffffu)) * w;
        r1 += bf2f((ushort)(u >> 16)) * w;
      }
    } else {
      float ald = alD[(size_t)d * 4 + h2];
      for (int e = half; e < dg; e += 2) {
        int s = srt[start + e];
        float a = alS[(size_t)s * 4 + h2] + ald;
        a = a > 0.f ? a : NEG_SLOPE * a;
        float w = __expf(a);
        unsigned u = *(const unsigned*)(hall + (size_t)s * 384 + rel * 128 + f2);
        r0 += bf2f((ushort)(u & 0xffffu)) * w;
        r1 += bf2f((ushort)(u >> 16)) * w;
      }
    }
    acc0 += r0 * rdn;
    acc1 += r1 * rdn;
    __syncthreads();   // protect denom_s/w_s reuse next relation
  }
  // combine the two edge-parity halves (reuse w_s as scratch)
  if (half == 1) {
    w_s[lt * 2] = acc0;
    w_s[lt * 2 + 1] = acc1;
  }
  __syncthreads();
  if (half == 0) {
    float o0 = acc0 + w_s[lt * 2]     + bias[f2]     + bias[128 + f2]     + bias[256 + f2];
    float o1 = acc1 + w_s[lt * 2 + 1] + bias[f2 + 1] + bias[128 + f2 + 1] + bias[256 + f2 + 1];
    *(float2*)(out + (size_t)d * 128 + f2) = make_float2(o0, o1);
  }
}

extern "C" void kernel_launch(void* const* d_in, const int* in_sizes, int n_in,
                              void* d_out, int out_size, void* d_ws, size_t ws_size,
                              hipStream_t stream) {
  const float* x     = (const float*)d_in[0];
  const int*   ei[3] = {(const int*)d_in[1], (const int*)d_in[2], (const int*)d_in[3]};
  const float* W     = (const float*)d_in[4];
  const float* a_src = (const float*)d_in[5];
  const float* a_dst = (const float*)d_in[6];
  const float* bias  = (const float*)d_in[7];

  const int Fin = 256;
  const int N = in_sizes[0] / Fin;
  const int E0 = in_sizes[1] / 2, E1 = in_sizes[2] / 2, E2 = in_sizes[3] / 2;
  const int Etot = E0 + E1 + E2;
  const int n3 = 3 * N;
  const int NB = (n3 + 1023) >> 10;   // buckets of 1024 keys

  float* out = (float*)d_out;

  // ws layout (8B-aligned chunks first)
  char* p = (char*)d_ws;
  ushort* WbigT   = (ushort*)p;  p += (size_t)448 * 256 * 2;
  ushort* hall    = (ushort*)p;  p += (size_t)N * 384 * 2;
  float*  al      = (float*)p;   p += (size_t)6 * N * 4 * 4;
  uint2*  staging = (uint2*)p;   p += (size_t)Etot * 8;
  int*    deg     = (int*)p;     p += (size_t)n3 * 4;
  int*    bhist   = (int*)p;     p += NBMAX * 4;
  int*    offs    = (int*)p;     p += (size_t)n3 * 4;
  int*    cursor  = (int*)p;     p += (size_t)n3 * 4;
  int*    bsum    = (int*)p;     p += 256 * 4;
  int*    boffs   = (int*)p;     p += (NBMAX + 1) * 4;
  int*    bcur    = (int*)p;     p += NBMAX * 4;
  int*    srt     = (int*)p;     p += (size_t)Etot * 4;

  // prep combined weight matrix (bf16, transposed)
  prep_kernel<<<(448 * 256 + 255) / 256, 256, 0, stream>>>(W, a_src, a_dst, WbigT);

  // one MFMA GEMM for all relations + attention projections
  gemm_mfma_kernel<<<(N + 63) / 64, 256, 0, stream>>>(x, WbigT, hall, al, N);

  // CSR build with bucketed scatter
  hipMemsetAsync(deg, 0, ((size_t)n3 + NBMAX) * sizeof(int), stream);  // deg + bhist
  int cblk = min((Etot + 255) / 256, 2048);
  bucket_count<<<cblk, 256, 0, stream>>>(
      ei[0] + E0, ei[1] + E1, ei[2] + E2, E0, E1, E2, deg, bhist, N, NB);
  bucket_scan<<<1, 256, 0, stream>>>(bhist, boffs, bcur, NB, Etot);
  const int nb1 = (n3 + 1023) / 1024;
  scan1_kernel<<<nb1, 1024, 0, stream>>>(deg, offs, bsum, n3);
  scan2_kernel<<<1, 256, 0, stream>>>(bsum, nb1);
  scan3_kernel<<<(n3 + 1023) / 1024, 1024, 0, stream>>>(offs, cursor, bsum, n3);
  bucket_stage<<<512, 256, 0, stream>>>(
      ei[0], ei[0] + E0, ei[1], ei[1] + E1, ei[2], ei[2] + E2,
      E0, E1, E2, bcur, staging, N, NB);
  bucket_scatter<<<NB, 256, 0, stream>>>(staging, boffs, cursor, srt);

  // fused softmax + gather + bias, one block per dst row, all relations
  gat_fused_kernel<<<N, 128, 0, stream>>>(srt, offs, deg, hall, al, bias, out, N);
}

// Round 6
// 321.978 us; speedup vs baseline: 4.5209x; 1.4287x over previous
//
#include <hip/hip_runtime.h>
#include <hip/hip_bf16.h>

#define NEG_SLOPE 0.2f
#define NBMAX 320       // max buckets: 3N/512; N=50000 -> 293
#define KB    512       // keys per bucket
#define CHUNK 4864      // edges per bucket_stage block (LDS-cached)

typedef short bf16x8 __attribute__((ext_vector_type(8)));
typedef float f32x4 __attribute__((ext_vector_type(4)));

__device__ inline ushort f2bf(float f) {
  __hip_bfloat16 b = __float2bfloat16(f);
  return *(ushort*)&b;
}
__device__ inline float bf2f(ushort u) {
  unsigned int v = ((unsigned int)u) << 16;
  return *(float*)&v;
}

// ---------- prep: WbigT[448][256] bf16 = [W0|W1|W2|Wa_src,Wa_dst|pad]^T -----
__global__ void prep_kernel(const float* __restrict__ W,
                            const float* __restrict__ a_src,
                            const float* __restrict__ a_dst,
                            ushort* __restrict__ WbigT) {
  int i = blockIdx.x * blockDim.x + threadIdx.x;  // over 448*256
  if (i >= 448 * 256) return;
  int c = i >> 8, k = i & 255;
  float v = 0.f;
  if (c < 384) {
    int r = c >> 7, j = c & 127;
    v = W[((size_t)r * 256 + k) * 128 + j];
  } else if (c < 408) {
    int c6 = c - 384, r = c6 >> 3, hh = c6 & 7, hd = hh & 3;
    const float* a = (hh < 4 ? a_src : a_dst) + (r * 4 + hd) * 32;
    const float* wp = W + ((size_t)r * 256 + k) * 128 + hd * 32;
#pragma unroll
    for (int d = 0; d < 32; ++d) v += wp[d] * a[d];
  }
  WbigT[i] = f2bf(v);
}

// ---------- MFMA GEMM: [M,256] x [256,448], block owns 64 rows x ALL 448 cols
__global__ __launch_bounds__(256, 2)
void gemm_mfma_kernel(const float* __restrict__ x, const ushort* __restrict__ WT,
                      ushort* __restrict__ hall, float* __restrict__ al, int M) {
  __shared__ __align__(16) ushort As[64][40];
  __shared__ __align__(16) ushort Bs[448][40];
  const int bm = blockIdx.x * 64;
  const int t = threadIdx.x;
  const int l = t & 63;
  const int w = t >> 6;
  const int wm = (w >> 1) * 32;
  const int wn = (w & 1) * 224;
  const int lr = l & 15, lg = l >> 4;

  f32x4 acc[2][14];
#pragma unroll
  for (int i = 0; i < 2; ++i)
#pragma unroll
    for (int j = 0; j < 14; ++j) acc[i][j] = (f32x4){0.f, 0.f, 0.f, 0.f};

  for (int k0 = 0; k0 < 256; k0 += 32) {
    {
      int row = t >> 2, seg = t & 3;
      int grow = bm + row;
      float4 v0 = make_float4(0.f, 0.f, 0.f, 0.f), v1 = v0;
      if (grow < M) {
        const float* xp = x + (size_t)grow * 256 + k0 + seg * 8;
        v0 = *(const float4*)xp;
        v1 = *(const float4*)(xp + 4);
      }
      uint4 pk;
      pk.x = (unsigned)f2bf(v0.x) | ((unsigned)f2bf(v0.y) << 16);
      pk.y = (unsigned)f2bf(v0.z) | ((unsigned)f2bf(v0.w) << 16);
      pk.z = (unsigned)f2bf(v1.x) | ((unsigned)f2bf(v1.y) << 16);
      pk.w = (unsigned)f2bf(v1.z) | ((unsigned)f2bf(v1.w) << 16);
      *(uint4*)&As[row][seg * 8] = pk;
    }
#pragma unroll
    for (int p = 0; p < 7; ++p) {
      int idx = p * 256 + t;
      int nrow = idx >> 2, ch = idx & 3;
      *(uint4*)&Bs[nrow][ch * 8] =
          *(const uint4*)(WT + (size_t)nrow * 256 + k0 + ch * 8);
    }
    __syncthreads();

    bf16x8 afrag[2];
    afrag[0] = *(bf16x8*)&As[wm + lr][lg * 8];
    afrag[1] = *(bf16x8*)&As[wm + 16 + lr][lg * 8];
#pragma unroll
    for (int j = 0; j < 14; ++j) {
      bf16x8 bfrag = *(bf16x8*)&Bs[wn + j * 16 + lr][lg * 8];
      acc[0][j] = __builtin_amdgcn_mfma_f32_16x16x32_bf16(afrag[0], bfrag, acc[0][j], 0, 0, 0);
      acc[1][j] = __builtin_amdgcn_mfma_f32_16x16x32_bf16(afrag[1], bfrag, acc[1][j], 0, 0, 0);
    }
    __syncthreads();
  }

#pragma unroll
  for (int i = 0; i < 2; ++i) {
#pragma unroll
    for (int rr = 0; rr < 4; ++rr) {
      int grow = bm + wm + i * 16 + lg * 4 + rr;
      if (grow >= M) continue;
#pragma unroll
      for (int j = 0; j < 14; ++j) {
        int gcol = wn + j * 16 + lr;
        float c = acc[i][j][rr];
        if (gcol < 384) {
          hall[(size_t)grow * 384 + gcol] = f2bf(c);
        } else if (gcol < 408) {
          int c6 = gcol - 384, r = c6 >> 3, hh = c6 & 7;
          al[(((size_t)(hh < 4 ? 0 : 3) + r) * M + grow) * 4 + (hh & 3)] = c;
        }
      }
    }
  }
}

// ---------- edge decode helper ----------
__device__ inline void edge_decode(int i, int E0, int E1,
                                   const int* __restrict__ s0, const int* __restrict__ d0,
                                   const int* __restrict__ s1, const int* __restrict__ d1,
                                   const int* __restrict__ s2, const int* __restrict__ d2,
                                   int N, int& src, int& key) {
  if (i < E0)            { src = s0[i];            key = d0[i]; }
  else if (i < E0 + E1)  { src = s1[i - E0];       key = N + d1[i - E0]; }
  else                   { src = s2[i - E0 - E1];  key = 2 * N + d2[i - E0 - E1]; }
}

// ---------- bhist_count: per-bucket histogram only (LDS-aggregated) ----------
__global__ __launch_bounds__(256)
void bhist_count(const int* __restrict__ d0, const int* __restrict__ d1,
                 const int* __restrict__ d2, int E0, int E1, int E2,
                 int* __restrict__ bhist, int N, int NB) {
  __shared__ int lh[NBMAX];
  int t = threadIdx.x;
  for (int b = t; b < NB; b += 256) lh[b] = 0;
  __syncthreads();
  int Etot = E0 + E1 + E2;
  for (int i = blockIdx.x * 256 + t; i < Etot; i += gridDim.x * 256) {
    int key;
    if (i < E0)           key = d0[i];
    else if (i < E0 + E1) key = N + d1[i - E0];
    else                  key = 2 * N + d2[i - E0 - E1];
    atomicAdd(&lh[key >> 9], 1);
  }
  __syncthreads();
  for (int b = t; b < NB; b += 256) {
    int v = lh[b];
    if (v) atomicAdd(&bhist[b], v);
  }
}

// ---------- bucket_scan: exclusive scan over NB<=512 buckets, 512 threads ----
__global__ __launch_bounds__(512)
void bucket_scan(const int* __restrict__ bhist, int* __restrict__ boffs,
                 int* __restrict__ bcur, int* __restrict__ offs,
                 int nb, int etot, int n3) {
  __shared__ int wsum[8];
  int t = threadIdx.x, lane = t & 63, wid = t >> 6;
  int v = (t < nb) ? bhist[t] : 0;
  int sv = v;
#pragma unroll
  for (int d = 1; d < 64; d <<= 1) {
    int u = __shfl_up(sv, d);
    if (lane >= d) sv += u;
  }
  if (lane == 63) wsum[wid] = sv;
  __syncthreads();
  if (t < 8) {
    int ws = wsum[t];
#pragma unroll
    for (int d = 1; d < 8; d <<= 1) {
      int u = __shfl_up(ws, d);
      if (t >= d) ws += u;
    }
    wsum[t] = ws;
  }
  __syncthreads();
  int excl = (wid ? wsum[wid - 1] : 0) + sv - v;
  if (t < nb) { boffs[t] = excl; bcur[t] = excl; }
  if (t == 0) { boffs[nb] = etot; offs[n3] = etot; }
}

// ---------- bucket_stage: LDS-cached slice, group edges by bucket ----------
__global__ __launch_bounds__(256)
void bucket_stage(const int* __restrict__ s0, const int* __restrict__ d0,
                  const int* __restrict__ s1, const int* __restrict__ d1,
                  const int* __restrict__ s2, const int* __restrict__ d2,
                  int E0, int E1, int E2,
                  int* __restrict__ bcur, uint2* __restrict__ staging,
                  int N, int NB) {
  __shared__ uint2 es[CHUNK];
  __shared__ int lh[NBMAX];
  __shared__ int lb[NBMAX];
  int t = threadIdx.x;
  int Etot = E0 + E1 + E2;
  int lo = blockIdx.x * CHUNK;
  int hi = min(lo + CHUNK, Etot);
  int n = hi - lo;
  for (int b = t; b < NB; b += 256) lh[b] = 0;
  __syncthreads();
  for (int i = t; i < n; i += 256) {
    int src, key;
    edge_decode(lo + i, E0, E1, s0, d0, s1, d1, s2, d2, N, src, key);
    es[i] = make_uint2((unsigned)src, (unsigned)key);
    atomicAdd(&lh[key >> 9], 1);
  }
  __syncthreads();
  for (int b = t; b < NB; b += 256) {
    int v = lh[b];
    lb[b] = v ? atomicAdd(&bcur[b], v) : 0;
    lh[b] = 0;
  }
  __syncthreads();
  for (int i = t; i < n; i += 256) {
    uint2 se = es[i];
    int b = se.y >> 9;
    int pos = lb[b] + atomicAdd(&lh[b], 1);
    staging[pos] = se;
  }
}

// ---------- bucket_sort: one block per bucket; LDS count+scan+scatter -------
// writes the offs[] window for its 512 keys (coalesced) and srt[] (L2-local)
__global__ __launch_bounds__(512)
void bucket_sort(const uint2* __restrict__ staging, const int* __restrict__ boffs,
                 int* __restrict__ offs, int* __restrict__ srt, int n3) {
  __shared__ int cnt[KB];
  __shared__ int cur[KB];
  __shared__ int wsum[8];
  const int b = blockIdx.x;
  const int base = b * KB;
  const int lo = boffs[b], hi = boffs[b + 1];
  const int t = threadIdx.x;
  cnt[t] = 0;
  __syncthreads();
  for (int i = lo + t; i < hi; i += 512)
    atomicAdd(&cnt[staging[i].y - base], 1);
  __syncthreads();
  // exclusive scan of cnt[0..511]
  int lane = t & 63, wid = t >> 6;
  int v = cnt[t];
  int sv = v;
#pragma unroll
  for (int d = 1; d < 64; d <<= 1) {
    int u = __shfl_up(sv, d);
    if (lane >= d) sv += u;
  }
  if (lane == 63) wsum[wid] = sv;
  __syncthreads();
  if (t < 8) {
    int ws = wsum[t];
#pragma unroll
    for (int d = 1; d < 8; d <<= 1) {
      int u = __shfl_up(ws, d);
      if (t >= d) ws += u;
    }
    wsum[t] = ws;
  }
  __syncthreads();
  int excl = lo + (wid ? wsum[wid - 1] : 0) + sv - v;
  cur[t] = excl;
  if (base + t < n3) offs[base + t] = excl;
  __syncthreads();
  for (int i = lo + t; i < hi; i += 512) {
    uint2 se = staging[i];
    int p = atomicAdd(&cur[se.y - base], 1);
    srt[p] = (int)se.x;
  }
}

// ---------- single-pass fused softmax+gather, one block per dst node --------
__global__ __launch_bounds__(128)
void gat_fused_kernel(const int* __restrict__ srt, const int* __restrict__ offs,
                      const ushort* __restrict__ hall,
                      const float* __restrict__ al,
                      const float* __restrict__ bias,
                      float* __restrict__ out, int N) {
  const int d = blockIdx.x;
  const int t = threadIdx.x;
  const int half = t >> 6;      // edge parity handled by this wave
  const int lt = t & 63;
  const int f2 = lt * 2;        // feature pair (f2, f2+1), same head
  const int h2 = lt >> 4;       // head = f2>>5

  __shared__ float slab[3][64][3];
  float res0[3], res1[3], resd[3];   // half==0 partials per relation

#pragma unroll
  for (int rel = 0; rel < 3; ++rel) {
    const int key = rel * N + d;
    const int start = offs[key];
    const int dg = offs[key + 1] - start;
    const float* alS = al + (size_t)rel * N * 4;
    const float ald = al[((size_t)(3 + rel) * N + d) * 4 + h2];
    float r0 = 0.f, r1 = 0.f, dl = 0.f;
#pragma unroll 2
    for (int e = half; e < dg; e += 2) {
      int s = srt[start + e];
      float a = alS[(size_t)s * 4 + h2] + ald;
      a = a > 0.f ? a : NEG_SLOPE * a;
      float ex = __expf(a);
      dl += ex;
      unsigned u = *(const unsigned*)(hall + (size_t)s * 384 + rel * 128 + f2);
      r0 += bf2f((ushort)(u & 0xffffu)) * ex;
      r1 += bf2f((ushort)(u >> 16)) * ex;
    }
    if (half) {
      slab[rel][lt][0] = r0; slab[rel][lt][1] = r1; slab[rel][lt][2] = dl;
    } else {
      res0[rel] = r0; res1[rel] = r1; resd[rel] = dl;
    }
  }
  __syncthreads();
  if (half == 0) {
    float o0 = bias[f2]     + bias[128 + f2]     + bias[256 + f2];
    float o1 = bias[f2 + 1] + bias[128 + f2 + 1] + bias[256 + f2 + 1];
#pragma unroll
    for (int rel = 0; rel < 3; ++rel) {
      float rdn = 1.f / (resd[rel] + slab[rel][lt][2] + 1e-16f);
      o0 += (res0[rel] + slab[rel][lt][0]) * rdn;
      o1 += (res1[rel] + slab[rel][lt][1]) * rdn;
    }
    *(float2*)(out + (size_t)d * 128 + f2) = make_float2(o0, o1);
  }
}

extern "C" void kernel_launch(void* const* d_in, const int* in_sizes, int n_in,
                              void* d_out, int out_size, void* d_ws, size_t ws_size,
                              hipStream_t stream) {
  const float* x     = (const float*)d_in[0];
  const int*   ei[3] = {(const int*)d_in[1], (const int*)d_in[2], (const int*)d_in[3]};
  const float* W     = (const float*)d_in[4];
  const float* a_src = (const float*)d_in[5];
  const float* a_dst = (const float*)d_in[6];
  const float* bias  = (const float*)d_in[7];

  const int Fin = 256;
  const int N = in_sizes[0] / Fin;
  const int E0 = in_sizes[1] / 2, E1 = in_sizes[2] / 2, E2 = in_sizes[3] / 2;
  const int Etot = E0 + E1 + E2;
  const int n3 = 3 * N;
  const int NB = (n3 + KB - 1) / KB;   // 512-key buckets

  float* out = (float*)d_out;

  // ws layout (8B-aligned blocks first)
  char* p = (char*)d_ws;
  ushort* WbigT   = (ushort*)p;  p += (size_t)448 * 256 * 2;
  ushort* hall    = (ushort*)p;  p += (size_t)N * 384 * 2;
  float*  al      = (float*)p;   p += (size_t)6 * N * 4 * 4;
  uint2*  staging = (uint2*)p;   p += (size_t)Etot * 8;
  int*    offs    = (int*)p;     p += ((size_t)n3 + 1) * 4;
  int*    bhist   = (int*)p;     p += NBMAX * 4;
  int*    boffs   = (int*)p;     p += (NBMAX + 1) * 4;
  int*    bcur    = (int*)p;     p += NBMAX * 4;
  int*    srt     = (int*)p;     p += (size_t)Etot * 4;

  // prep combined weight matrix (bf16, transposed)
  prep_kernel<<<(448 * 256 + 255) / 256, 256, 0, stream>>>(W, a_src, a_dst, WbigT);

  // one MFMA GEMM for all relations + attention projections
  gemm_mfma_kernel<<<(N + 63) / 64, 256, 0, stream>>>(x, WbigT, hall, al, N);

  // CSR build: bucket histogram -> scan -> stage -> per-bucket counting sort
  hipMemsetAsync(bhist, 0, NBMAX * sizeof(int), stream);
  int cblk = min((Etot + 255) / 256, 2048);
  bhist_count<<<cblk, 256, 0, stream>>>(
      ei[0] + E0, ei[1] + E1, ei[2] + E2, E0, E1, E2, bhist, N, NB);
  bucket_scan<<<1, 512, 0, stream>>>(bhist, boffs, bcur, offs, NB, Etot, n3);
  bucket_stage<<<(Etot + CHUNK - 1) / CHUNK, 256, 0, stream>>>(
      ei[0], ei[0] + E0, ei[1], ei[1] + E1, ei[2], ei[2] + E2,
      E0, E1, E2, bcur, staging, N, NB);
  bucket_sort<<<NB, 512, 0, stream>>>(staging, boffs, offs, srt, n3);

  // single-pass fused softmax + gather + bias, one block per dst row
  gat_fused_kernel<<<N, 128, 0, stream>>>(srt, offs, hall, al, bias, out, N);
}